// Round 2
// baseline (2330.823 us; speedup 1.0000x reference)
//
#include <hip/hip_runtime.h>

#define NN 50000
#define DD 128
#define NE 600000
#define NP 200000
#define NS 300000
#define NU 256

// ---- degrees: deg[0..NN) = out-degree(src), deg[NN..2NN) = in-degree(dst) ----
__global__ void k_degree(const int* __restrict__ ei, int* __restrict__ deg) {
    int e = blockIdx.x * 256 + threadIdx.x;
    if (e < NE) {
        atomicAdd(&deg[ei[e]], 1);
        atomicAdd(&deg[NN + ei[NE + e]], 1);
    }
}

__global__ void k_rsqrt(const int* __restrict__ deg, float* __restrict__ r) {
    int n = blockIdx.x * 256 + threadIdx.x;
    if (n < 2 * NN) r[n] = rsqrtf((float)max(deg[n], 1));
}

// ---- C[64 rows x 128] = rowscale(A) @ W, fp32, LDS-tiled ----
__global__ __launch_bounds__(256) void k_gemm_rs(const float* __restrict__ A,
                                                 const float* __restrict__ rs,
                                                 const float* __restrict__ W,
                                                 float* __restrict__ C) {
    __shared__ float As[64][36];    // +4 pad: conflict-free float4 stores, broadcast reads
    __shared__ float Ws[32][132];   // +4 pad: conflict-free float4 stores, 16B-aligned reads
    int tid = threadIdx.x;
    int tx = tid & 31;              // output col group: cols tx*4..tx*4+3
    int ty = tid >> 5;              // output row group: rows ty*8..ty*8+7
    int row0 = blockIdx.x * 64;

    float acc[8][4];
#pragma unroll
    for (int i = 0; i < 8; ++i)
#pragma unroll
        for (int c = 0; c < 4; ++c) acc[i][c] = 0.f;

    for (int kc = 0; kc < 4; ++kc) {
        // stage A chunk [64][32]
        {
            int c4 = tid & 7, rr = tid >> 3;            // rr 0..31
#pragma unroll
            for (int p = 0; p < 2; ++p) {
                int r2 = rr + 32 * p;
                int gr = row0 + r2; if (gr > NN - 1) gr = NN - 1;
                float4 v = *(const float4*)(A + (size_t)gr * DD + kc * 32 + c4 * 4);
                *(float4*)&As[r2][c4 * 4] = v;
            }
        }
        // stage W chunk [32][128]
        {
            int j4 = tid & 31, k0 = tid >> 5;           // k0 0..7
#pragma unroll
            for (int p = 0; p < 4; ++p) {
                int kk = k0 + 8 * p;
                float4 v = *(const float4*)(W + (size_t)(kc * 32 + kk) * DD + j4 * 4);
                *(float4*)&Ws[kk][j4 * 4] = v;
            }
        }
        __syncthreads();
#pragma unroll
        for (int k = 0; k < 32; ++k) {
            float4 wv = *(const float4*)&Ws[k][tx * 4];
#pragma unroll
            for (int i = 0; i < 8; ++i) {
                float av = As[ty * 8 + i][k];           // wave-broadcast (free)
                acc[i][0] += av * wv.x;
                acc[i][1] += av * wv.y;
                acc[i][2] += av * wv.z;
                acc[i][3] += av * wv.w;
            }
        }
        __syncthreads();
    }
#pragma unroll
    for (int i = 0; i < 8; ++i) {
        int gr = row0 + ty * 8 + i;
        if (gr < NN) {
            float s = rs[gr];
            float4 o = {acc[i][0] * s, acc[i][1] * s, acc[i][2] * s, acc[i][3] * s};
            *(float4*)(C + (size_t)gr * DD + tx * 4) = o;
        }
    }
}

// ---- scatter-add: agg[dst] += T[src], 32 lanes/edge, float4 gather ----
__global__ void k_scatter(const float* __restrict__ T, const int* __restrict__ ei,
                          float* __restrict__ agg) {
    int tid = blockIdx.x * 256 + threadIdx.x;
    int e = tid >> 5;
    if (e >= NE) return;
    int j = (tid & 31) << 2;
    int s = ei[e], d = ei[NE + e];
    float4 v = *(const float4*)(T + (size_t)s * DD + j);
    float* ap = agg + (size_t)d * DD + j;
    unsafeAtomicAdd(ap + 0, v.x);
    unsafeAtomicAdd(ap + 1, v.y);
    unsafeAtomicAdd(ap + 2, v.z);
    unsafeAtomicAdd(ap + 3, v.w);
}

// ---- H = agg * r_in + bias ----
__global__ void k_finalize(const float* __restrict__ agg, const float* __restrict__ r_in,
                           const float* __restrict__ b, float* __restrict__ H) {
    int t = blockIdx.x * 256 + threadIdx.x;   // t < NN*32
    int n = t >> 5, c = (t & 31) << 2;
    float rv = r_in[n];
    float4 a = *(const float4*)(agg + (size_t)t * 4);
    float4 bb = *(const float4*)(b + c);
    float4 o = {a.x * rv + bb.x, a.y * rv + bb.y, a.z * rv + bb.z, a.w * rv + bb.w};
    *(float4*)(H + (size_t)t * 4) = o;
}

// ---- per-node MLP: P[n] = softmax(relu(h2[n]@dW + db)@oW + ob), 16 nodes/block ----
__global__ __launch_bounds__(256) void k_mlp(const float* __restrict__ H2,
                                             const float* __restrict__ dW,
                                             const float* __restrict__ db,
                                             const float* __restrict__ oW,
                                             const float* __restrict__ ob,
                                             float* __restrict__ P) {
    __shared__ float Hs[16][132];
    __shared__ float red[4][16][2];
    int tid = threadIdx.x;
    int nb = blockIdx.x * 16;
    {
        int c4 = tid & 31, r = tid >> 5;   // r 0..7
#pragma unroll
        for (int p = 0; p < 2; ++p) {
            int rr = r + 8 * p;
            float4 v = *(const float4*)(H2 + (size_t)(nb + rr) * DD + c4 * 4);
            *(float4*)&Hs[rr][c4 * 4] = v;
        }
    }
    __syncthreads();
    float acc[16];
    float bj = db[tid];
#pragma unroll
    for (int r = 0; r < 16; ++r) acc[r] = bj;
    for (int k = 0; k < DD; ++k) {
        float wv = dW[(size_t)k * NU + tid];
#pragma unroll
        for (int r = 0; r < 16; ++r) acc[r] += Hs[r][k] * wv;   // Hs broadcast
    }
    float w0 = oW[2 * tid], w1 = oW[2 * tid + 1];
#pragma unroll
    for (int r = 0; r < 16; ++r) {
        float h = fmaxf(acc[r], 0.f);
        float a0 = h * w0, a1 = h * w1;
#pragma unroll
        for (int off = 32; off > 0; off >>= 1) {
            a0 += __shfl_down(a0, off);
            a1 += __shfl_down(a1, off);
        }
        if ((tid & 63) == 0) { red[tid >> 6][r][0] = a0; red[tid >> 6][r][1] = a1; }
    }
    __syncthreads();
    if (tid < 16) {
        float l0 = red[0][tid][0] + red[1][tid][0] + red[2][tid][0] + red[3][tid][0] + ob[0];
        float l1 = red[0][tid][1] + red[1][tid][1] + red[2][tid][1] + red[3][tid][1] + ob[1];
        float m = fmaxf(l0, l1);
        float e0 = __expf(l0 - m), e1 = __expf(l1 - m);
        float inv = 1.f / (e0 + e1);
        float2 pr = {e0 * inv, e1 * inv};
        *(float2*)(P + 2 * (nb + tid)) = pr;
    }
}

// ---- final gather: out[i] = P[oe_flat[set_idx[i]]] ----
__global__ void k_gather(const int* __restrict__ sidx, const int* __restrict__ oe,
                         const float* __restrict__ P, float* __restrict__ out) {
    int i = blockIdx.x * 256 + threadIdx.x;
    if (i >= NS) return;
    int node = oe[sidx[i]];
    float2 v = *(const float2*)(P + 2 * node);
    *(float2*)(out + 2 * i) = v;
}

extern "C" void kernel_launch(void* const* d_in, const int* in_sizes, int n_in,
                              void* d_out, int out_size, void* d_ws, size_t ws_size,
                              hipStream_t stream) {
    const float* node_state = (const float*)d_in[0];
    const int* ei   = (const int*)d_in[1];
    const int* oe   = (const int*)d_in[2];
    const int* sidx = (const int*)d_in[3];
    const float* W1 = (const float*)d_in[4];
    const float* b1 = (const float*)d_in[5];
    const float* W2 = (const float*)d_in[6];
    const float* b2 = (const float*)d_in[7];
    const float* dW = (const float*)d_in[8];
    const float* db = (const float*)d_in[9];
    const float* oW = (const float*)d_in[10];
    const float* ob = (const float*)d_in[11];
    float* out = (float*)d_out;

    char* ws = (char*)d_ws;
    size_t off = 0;
    auto carve = [&](size_t bytes) -> char* {
        char* p = ws + off;
        off = (off + bytes + 255) & ~(size_t)255;
        return p;
    };
    int*   deg = (int*)carve((size_t)2 * NN * 4);
    float* r   = (float*)carve((size_t)2 * NN * 4);
    float* t   = (float*)carve((size_t)NN * DD * 4);
    float* agg = (float*)carve((size_t)NN * DD * 4);
    float* h   = (float*)carve((size_t)NN * DD * 4);
    float* P   = t;   // alias: t is dead after the second scatter

    float* r_out = r;
    float* r_in  = r + NN;

    hipMemsetAsync(deg, 0, (size_t)2 * NN * 4, stream);
    k_degree<<<(NE + 255) / 256, 256, 0, stream>>>(ei, deg);
    k_rsqrt<<<(2 * NN + 255) / 256, 256, 0, stream>>>(deg, r);

    // layer 1
    hipMemsetAsync(agg, 0, (size_t)NN * DD * 4, stream);
    k_gemm_rs<<<(NN + 63) / 64, 256, 0, stream>>>(node_state, r_out, W1, t);
    k_scatter<<<NE * 32 / 256, 256, 0, stream>>>(t, ei, agg);
    k_finalize<<<NN * 32 / 256, 256, 0, stream>>>(agg, r_in, b1, h);

    // layer 2
    hipMemsetAsync(agg, 0, (size_t)NN * DD * 4, stream);
    k_gemm_rs<<<(NN + 63) / 64, 256, 0, stream>>>(h, r_out, W2, t);
    k_scatter<<<NE * 32 / 256, 256, 0, stream>>>(t, ei, agg);
    k_finalize<<<NN * 32 / 256, 256, 0, stream>>>(agg, r_in, b2, h);

    // per-node MLP + softmax, then gather to output
    k_mlp<<<NN / 16, 256, 0, stream>>>(h, dW, db, oW, ob, P);
    k_gather<<<(NS + 255) / 256, 256, 0, stream>>>(sidx, oe, P, out);
}

// Round 3
// 461.547 us; speedup vs baseline: 5.0500x; 5.0500x over previous
//
#include <hip/hip_runtime.h>

#define NN 50000
#define DD 128
#define NE 600000
#define NP 200000
#define NS 300000
#define NU 256

// ---- degrees: deg[0..NN) = out-degree(src), deg[NN..2NN) = in-degree(dst) ----
__global__ void k_degree(const int* __restrict__ ei, int* __restrict__ deg) {
    int e = blockIdx.x * 256 + threadIdx.x;
    if (e < NE) {
        atomicAdd(&deg[ei[e]], 1);
        atomicAdd(&deg[NN + ei[NE + e]], 1);
    }
}

__global__ void k_rsqrt(const int* __restrict__ deg, float* __restrict__ r) {
    int n = blockIdx.x * 256 + threadIdx.x;
    if (n < 2 * NN) r[n] = rsqrtf((float)max(deg[n], 1));
}

// ---- single-block exclusive prefix sum of deg_in -> row_ptr[NN+1] ----
__global__ __launch_bounds__(1024) void k_scan(const int* __restrict__ deg_in,
                                               int* __restrict__ row_ptr) {
    __shared__ int wsum[16];
    __shared__ int woff[16];
    __shared__ int carry_s;
    __shared__ int total_s;
    int tid = threadIdx.x, lane = tid & 63, w = tid >> 6;
    if (tid == 0) carry_s = 0;
    __syncthreads();
    for (int base = 0; base < NN; base += 1024) {
        int i = base + tid;
        int v = (i < NN) ? deg_in[i] : 0;
        int x = v;                       // wave-inclusive scan
#pragma unroll
        for (int off = 1; off < 64; off <<= 1) {
            int y = __shfl_up(x, off);
            if (lane >= off) x += y;
        }
        if (lane == 63) wsum[w] = x;
        __syncthreads();
        if (w == 0 && lane < 16) {
            int s = wsum[lane];
            int xs = s;
#pragma unroll
            for (int off = 1; off < 16; off <<= 1) {
                int y = __shfl_up(xs, off);
                if (lane >= off) xs += y;
            }
            woff[lane] = xs - s;         // exclusive wave offset
            if (lane == 15) total_s = xs;
        }
        __syncthreads();
        if (i < NN) row_ptr[i] = carry_s + woff[w] + x - v;
        __syncthreads();                 // all reads of carry_s done
        if (tid == 0) carry_s += total_s;
        __syncthreads();
    }
    if (threadIdx.x == 0) row_ptr[NN] = carry_s;
}

// ---- bucket edges by dst: col[row_ptr[dst] + cursor[dst]++] = src ----
__global__ void k_bucket(const int* __restrict__ ei, const int* __restrict__ row_ptr,
                         int* __restrict__ cursor, int* __restrict__ col) {
    int e = blockIdx.x * 256 + threadIdx.x;
    if (e < NE) {
        int d = ei[NE + e];
        int pos = atomicAdd(&cursor[d], 1);
        col[row_ptr[d] + pos] = ei[e];
    }
}

// ---- C[64 rows x 128] = rowscale(A) @ W, fp32, LDS-tiled ----
__global__ __launch_bounds__(256) void k_gemm_rs(const float* __restrict__ A,
                                                 const float* __restrict__ rs,
                                                 const float* __restrict__ W,
                                                 float* __restrict__ C) {
    __shared__ float As[64][36];
    __shared__ float Ws[32][132];
    int tid = threadIdx.x;
    int tx = tid & 31;
    int ty = tid >> 5;
    int row0 = blockIdx.x * 64;

    float acc[8][4];
#pragma unroll
    for (int i = 0; i < 8; ++i)
#pragma unroll
        for (int c = 0; c < 4; ++c) acc[i][c] = 0.f;

    for (int kc = 0; kc < 4; ++kc) {
        {
            int c4 = tid & 7, rr = tid >> 3;
#pragma unroll
            for (int p = 0; p < 2; ++p) {
                int r2 = rr + 32 * p;
                int gr = row0 + r2; if (gr > NN - 1) gr = NN - 1;
                float4 v = *(const float4*)(A + (size_t)gr * DD + kc * 32 + c4 * 4);
                *(float4*)&As[r2][c4 * 4] = v;
            }
        }
        {
            int j4 = tid & 31, k0 = tid >> 5;
#pragma unroll
            for (int p = 0; p < 4; ++p) {
                int kk = k0 + 8 * p;
                float4 v = *(const float4*)(W + (size_t)(kc * 32 + kk) * DD + j4 * 4);
                *(float4*)&Ws[kk][j4 * 4] = v;
            }
        }
        __syncthreads();
#pragma unroll
        for (int k = 0; k < 32; ++k) {
            float4 wv = *(const float4*)&Ws[k][tx * 4];
#pragma unroll
            for (int i = 0; i < 8; ++i) {
                float av = As[ty * 8 + i][k];
                acc[i][0] += av * wv.x;
                acc[i][1] += av * wv.y;
                acc[i][2] += av * wv.z;
                acc[i][3] += av * wv.w;
            }
        }
        __syncthreads();
    }
#pragma unroll
    for (int i = 0; i < 8; ++i) {
        int gr = row0 + ty * 8 + i;
        if (gr < NN) {
            float s = rs[gr];
            float4 o = {acc[i][0] * s, acc[i][1] * s, acc[i][2] * s, acc[i][3] * s};
            *(float4*)(C + (size_t)gr * DD + tx * 4) = o;
        }
    }
}

// ---- CSR aggregate + fused finalize: H[n] = (sum_{s in N(n)} T[s]) * r_in[n] + b ----
// one wave per node, 2 channels per lane; indices broadcast via shfl
__global__ __launch_bounds__(256) void k_aggregate(const float* __restrict__ T,
                                                   const int* __restrict__ row_ptr,
                                                   const int* __restrict__ col,
                                                   const float* __restrict__ r_in,
                                                   const float* __restrict__ b,
                                                   float* __restrict__ H) {
    int node = blockIdx.x * 4 + (threadIdx.x >> 6);
    if (node >= NN) return;
    int lane = threadIdx.x & 63;
    int beg = row_ptr[node], end = row_ptr[node + 1];
    float2 acc = {0.f, 0.f};
    for (int base = beg; base < end; base += 64) {
        int m = end - base; if (m > 64) m = 64;
        int myidx = (lane < m) ? col[base + lane] : 0;
        for (int j = 0; j < m; ++j) {
            int s = __shfl(myidx, j);
            float2 v = *(const float2*)(T + (size_t)s * DD + lane * 2);
            acc.x += v.x; acc.y += v.y;
        }
    }
    float rv = r_in[node];
    float2 bb = *(const float2*)(b + lane * 2);
    float2 o = {acc.x * rv + bb.x, acc.y * rv + bb.y};
    *(float2*)(H + (size_t)node * DD + lane * 2) = o;
}

// ---- per-node MLP: P[n] = softmax(relu(h2[n]@dW + db)@oW + ob), 16 nodes/block ----
__global__ __launch_bounds__(256) void k_mlp(const float* __restrict__ H2,
                                             const float* __restrict__ dW,
                                             const float* __restrict__ db,
                                             const float* __restrict__ oW,
                                             const float* __restrict__ ob,
                                             float* __restrict__ P) {
    __shared__ float Hs[16][132];
    __shared__ float red[4][16][2];
    int tid = threadIdx.x;
    int nb = blockIdx.x * 16;
    {
        int c4 = tid & 31, rr0 = tid >> 5;
#pragma unroll
        for (int p = 0; p < 2; ++p) {
            int rr = rr0 + 8 * p;
            float4 v = *(const float4*)(H2 + (size_t)(nb + rr) * DD + c4 * 4);
            *(float4*)&Hs[rr][c4 * 4] = v;
        }
    }
    __syncthreads();
    float acc[16];
    float bj = db[tid];
#pragma unroll
    for (int r = 0; r < 16; ++r) acc[r] = bj;
    for (int k = 0; k < DD; ++k) {
        float wv = dW[(size_t)k * NU + tid];
#pragma unroll
        for (int r = 0; r < 16; ++r) acc[r] += Hs[r][k] * wv;
    }
    float w0 = oW[2 * tid], w1 = oW[2 * tid + 1];
#pragma unroll
    for (int r = 0; r < 16; ++r) {
        float h = fmaxf(acc[r], 0.f);
        float a0 = h * w0, a1 = h * w1;
#pragma unroll
        for (int off = 32; off > 0; off >>= 1) {
            a0 += __shfl_down(a0, off);
            a1 += __shfl_down(a1, off);
        }
        if ((tid & 63) == 0) { red[tid >> 6][r][0] = a0; red[tid >> 6][r][1] = a1; }
    }
    __syncthreads();
    if (tid < 16) {
        float l0 = red[0][tid][0] + red[1][tid][0] + red[2][tid][0] + red[3][tid][0] + ob[0];
        float l1 = red[0][tid][1] + red[1][tid][1] + red[2][tid][1] + red[3][tid][1] + ob[1];
        float m = fmaxf(l0, l1);
        float e0 = __expf(l0 - m), e1 = __expf(l1 - m);
        float inv = 1.f / (e0 + e1);
        float2 pr = {e0 * inv, e1 * inv};
        *(float2*)(P + 2 * (nb + tid)) = pr;
    }
}

// ---- final gather: out[i] = P[oe_flat[set_idx[i]]] ----
__global__ void k_gather(const int* __restrict__ sidx, const int* __restrict__ oe,
                         const float* __restrict__ P, float* __restrict__ out) {
    int i = blockIdx.x * 256 + threadIdx.x;
    if (i >= NS) return;
    int node = oe[sidx[i]];
    float2 v = *(const float2*)(P + 2 * node);
    *(float2*)(out + 2 * i) = v;
}

extern "C" void kernel_launch(void* const* d_in, const int* in_sizes, int n_in,
                              void* d_out, int out_size, void* d_ws, size_t ws_size,
                              hipStream_t stream) {
    const float* node_state = (const float*)d_in[0];
    const int* ei   = (const int*)d_in[1];
    const int* oe   = (const int*)d_in[2];
    const int* sidx = (const int*)d_in[3];
    const float* W1 = (const float*)d_in[4];
    const float* b1 = (const float*)d_in[5];
    const float* W2 = (const float*)d_in[6];
    const float* b2 = (const float*)d_in[7];
    const float* dW = (const float*)d_in[8];
    const float* db = (const float*)d_in[9];
    const float* oW = (const float*)d_in[10];
    const float* ob = (const float*)d_in[11];
    float* out = (float*)d_out;

    char* ws = (char*)d_ws;
    size_t off = 0;
    auto carve = [&](size_t bytes) -> char* {
        char* p = ws + off;
        off = (off + bytes + 255) & ~(size_t)255;
        return p;
    };
    int*   deg     = (int*)carve((size_t)3 * NN * 4);   // deg_out | deg_in | cursor (one memset)
    int*   cursor  = deg + 2 * NN;
    float* r       = (float*)carve((size_t)2 * NN * 4);
    int*   row_ptr = (int*)carve((size_t)(NN + 1) * 4);
    int*   col     = (int*)carve((size_t)NE * 4);
    float* t       = (float*)carve((size_t)NN * DD * 4);
    float* h       = (float*)carve((size_t)NN * DD * 4);
    float* P       = t;   // alias: t is dead after the second aggregate

    float* r_out = r;
    float* r_in  = r + NN;
    int* deg_in  = deg + NN;

    // CSR build (once; reused for both layers)
    hipMemsetAsync(deg, 0, (size_t)3 * NN * 4, stream);
    k_degree<<<(NE + 255) / 256, 256, 0, stream>>>(ei, deg);
    k_rsqrt<<<(2 * NN + 255) / 256, 256, 0, stream>>>(deg, r);
    k_scan<<<1, 1024, 0, stream>>>(deg_in, row_ptr);
    k_bucket<<<(NE + 255) / 256, 256, 0, stream>>>(ei, row_ptr, cursor, col);

    // layer 1
    k_gemm_rs<<<(NN + 63) / 64, 256, 0, stream>>>(node_state, r_out, W1, t);
    k_aggregate<<<(NN + 3) / 4, 256, 0, stream>>>(t, row_ptr, col, r_in, b1, h);

    // layer 2
    k_gemm_rs<<<(NN + 63) / 64, 256, 0, stream>>>(h, r_out, W2, t);
    k_aggregate<<<(NN + 3) / 4, 256, 0, stream>>>(t, row_ptr, col, r_in, b2, h);

    // per-node MLP + softmax, then gather to output
    k_mlp<<<NN / 16, 256, 0, stream>>>(h, dW, db, oW, ob, P);
    k_gather<<<(NS + 255) / 256, 256, 0, stream>>>(sidx, oe, P, out);
}

// Round 4
// 330.837 us; speedup vs baseline: 7.0452x; 1.3951x over previous
//
#include <hip/hip_runtime.h>

#define NN 50000
#define DD 128
#define NE 600000
#define NP 200000
#define NS 300000
#define NU 256

typedef __attribute__((ext_vector_type(8))) short short8;
typedef __attribute__((ext_vector_type(4))) float floatx4;

__device__ inline float bf2f(unsigned int u16) {
    unsigned int x = u16 << 16;
    float f; __builtin_memcpy(&f, &x, 4); return f;
}
__device__ inline unsigned short f2bf(float f) {
    unsigned int x; __builtin_memcpy(&x, &f, 4);
    unsigned int lsb = (x >> 16) & 1u;
    x += 0x7fffu + lsb;
    return (unsigned short)(x >> 16);
}

// ---- degrees: deg[0..NN) = out-degree(src), deg[NN..2NN) = in-degree(dst) ----
__global__ void k_degree(const int* __restrict__ ei, int* __restrict__ deg) {
    int e = blockIdx.x * 256 + threadIdx.x;
    if (e < NE) {
        atomicAdd(&deg[ei[e]], 1);
        atomicAdd(&deg[NN + ei[NE + e]], 1);
    }
}

__global__ void k_rsqrt(const int* __restrict__ deg, float* __restrict__ r) {
    int n = blockIdx.x * 256 + threadIdx.x;
    if (n < 2 * NN) r[n] = rsqrtf((float)max(deg[n], 1));
}

// ---- single-block exclusive prefix sum of deg_in -> row_ptr[NN+1] ----
__global__ __launch_bounds__(1024) void k_scan(const int* __restrict__ deg_in,
                                               int* __restrict__ row_ptr) {
    __shared__ int wsum[16];
    __shared__ int woff[16];
    __shared__ int carry_s;
    __shared__ int total_s;
    int tid = threadIdx.x, lane = tid & 63, w = tid >> 6;
    if (tid == 0) carry_s = 0;
    __syncthreads();
    for (int base = 0; base < NN; base += 1024) {
        int i = base + tid;
        int v = (i < NN) ? deg_in[i] : 0;
        int x = v;
#pragma unroll
        for (int off = 1; off < 64; off <<= 1) {
            int y = __shfl_up(x, off);
            if (lane >= off) x += y;
        }
        if (lane == 63) wsum[w] = x;
        __syncthreads();
        if (w == 0 && lane < 16) {
            int s = wsum[lane];
            int xs = s;
#pragma unroll
            for (int off = 1; off < 16; off <<= 1) {
                int y = __shfl_up(xs, off);
                if (lane >= off) xs += y;
            }
            woff[lane] = xs - s;
            if (lane == 15) total_s = xs;
        }
        __syncthreads();
        if (i < NN) row_ptr[i] = carry_s + woff[w] + x - v;
        __syncthreads();
        if (tid == 0) carry_s += total_s;
        __syncthreads();
    }
    if (threadIdx.x == 0) row_ptr[NN] = carry_s;
}

// ---- bucket edges by dst ----
__global__ void k_bucket(const int* __restrict__ ei, const int* __restrict__ row_ptr,
                         int* __restrict__ cursor, int* __restrict__ col) {
    int e = blockIdx.x * 256 + threadIdx.x;
    if (e < NE) {
        int d = ei[NE + e];
        int pos = atomicAdd(&cursor[d], 1);
        col[row_ptr[d] + pos] = ei[e];
    }
}

// ---- transpose + bf16-cast weights: dst[c*R+r] = bf16(src[r*C+c]) ----
__global__ void k_castT(const float* __restrict__ src, unsigned short* __restrict__ dst,
                        int R, int C) {
    int t = blockIdx.x * 256 + threadIdx.x;
    if (t < R * C) {
        int r = t / C, c = t - r * C;
        dst[c * R + r] = f2bf(src[t]);
    }
}

// ---- MFMA GEMM: Cm[64x128 bf16] = rowscale(A[64x128]) @ B, BT[128][128] bf16 ----
template <bool ABF>
__global__ __launch_bounds__(256) void k_gemm_bf(const void* __restrict__ Ap,
                                                 const float* __restrict__ rs,
                                                 const unsigned short* __restrict__ BT,
                                                 unsigned short* __restrict__ Cm) {
    __shared__ unsigned short As[64][136];   // +8 pad: 2-way (free) banking on b128 reads
    __shared__ unsigned short Bs[128][136];
    int tid = threadIdx.x, lane = tid & 63, wave = tid >> 6;
    int quad = lane >> 4, l16 = lane & 15;
    int row0 = blockIdx.x * 64;

    if (ABF) {
        const unsigned short* A = (const unsigned short*)Ap;
#pragma unroll
        for (int p = 0; p < 4; ++p) {
            int fid = tid + p * 256;                 // 1024 x 16B
            int r = fid >> 4, c = fid & 15;
            int gr = row0 + r; if (gr > NN - 1) gr = NN - 1;
            *(uint4*)&As[r][c * 8] = *(const uint4*)(A + (size_t)gr * DD + c * 8);
        }
    } else {
        const float* A = (const float*)Ap;
#pragma unroll
        for (int p = 0; p < 8; ++p) {
            int fid = tid + p * 256;                 // 2048 x float4
            int r = fid >> 5, c = fid & 31;
            int gr = row0 + r; if (gr > NN - 1) gr = NN - 1;
            float4 v = *(const float4*)(A + (size_t)gr * DD + c * 4);
            ushort4 u;
            u.x = f2bf(v.x); u.y = f2bf(v.y); u.z = f2bf(v.z); u.w = f2bf(v.w);
            *(ushort4*)&As[r][c * 4] = u;
        }
    }
#pragma unroll
    for (int p = 0; p < 8; ++p) {
        int fid = tid + p * 256;                     // 2048 x 16B
        int r = fid >> 4, c = fid & 15;
        *(uint4*)&Bs[r][c * 8] = *(const uint4*)(BT + (size_t)r * DD + c * 8);
    }
    __syncthreads();

    short8 af[4];
#pragma unroll
    for (int ks = 0; ks < 4; ++ks)
        af[ks] = *(const short8*)&As[wave * 16 + l16][ks * 32 + quad * 8];
    floatx4 acc[8];
#pragma unroll
    for (int nt = 0; nt < 8; ++nt) acc[nt] = (floatx4){0.f, 0.f, 0.f, 0.f};
#pragma unroll
    for (int ks = 0; ks < 4; ++ks) {
#pragma unroll
        for (int nt = 0; nt < 8; ++nt) {
            short8 bf = *(const short8*)&Bs[nt * 16 + l16][ks * 32 + quad * 8];
            acc[nt] = __builtin_amdgcn_mfma_f32_16x16x32_bf16(af[ks], bf, acc[nt], 0, 0, 0);
        }
    }
    int rbase = row0 + wave * 16 + quad * 4;
#pragma unroll
    for (int r = 0; r < 4; ++r) {
        int gr = rbase + r;
        if (gr < NN) {
            float s = rs[gr];
#pragma unroll
            for (int nt = 0; nt < 8; ++nt)
                Cm[(size_t)gr * DD + nt * 16 + l16] = f2bf(acc[nt][r] * s);
        }
    }
}

// ---- CSR aggregate + fused finalize: H[n] = bf16((sum T[s]) * r_in[n] + b) ----
__global__ __launch_bounds__(256) void k_aggregate(const unsigned short* __restrict__ T,
                                                   const int* __restrict__ row_ptr,
                                                   const int* __restrict__ col,
                                                   const float* __restrict__ r_in,
                                                   const float* __restrict__ b,
                                                   unsigned short* __restrict__ H) {
    int node = blockIdx.x * 4 + (threadIdx.x >> 6);
    if (node >= NN) return;
    int lane = threadIdx.x & 63;
    int beg = row_ptr[node], end = row_ptr[node + 1];
    float a0 = 0.f, a1 = 0.f;
    for (int base = beg; base < end; base += 64) {
        int m = end - base; if (m > 64) m = 64;
        int myidx = (lane < m) ? col[base + lane] : 0;
        int j = 0;
        for (; j + 4 <= m; j += 4) {
            int s0 = __shfl(myidx, j), s1 = __shfl(myidx, j + 1);
            int s2 = __shfl(myidx, j + 2), s3 = __shfl(myidx, j + 3);
            unsigned int v0 = *(const unsigned int*)(T + (size_t)s0 * DD + lane * 2);
            unsigned int v1 = *(const unsigned int*)(T + (size_t)s1 * DD + lane * 2);
            unsigned int v2 = *(const unsigned int*)(T + (size_t)s2 * DD + lane * 2);
            unsigned int v3 = *(const unsigned int*)(T + (size_t)s3 * DD + lane * 2);
            a0 += bf2f(v0 & 0xffff) + bf2f(v1 & 0xffff) + bf2f(v2 & 0xffff) + bf2f(v3 & 0xffff);
            a1 += bf2f(v0 >> 16) + bf2f(v1 >> 16) + bf2f(v2 >> 16) + bf2f(v3 >> 16);
        }
        for (; j < m; ++j) {
            int s = __shfl(myidx, j);
            unsigned int v = *(const unsigned int*)(T + (size_t)s * DD + lane * 2);
            a0 += bf2f(v & 0xffff);
            a1 += bf2f(v >> 16);
        }
    }
    float rv = r_in[node];
    float o0 = a0 * rv + b[lane * 2];
    float o1 = a1 * rv + b[lane * 2 + 1];
    unsigned int packed = (unsigned int)f2bf(o0) | ((unsigned int)f2bf(o1) << 16);
    *(unsigned int*)(H + (size_t)node * DD + lane * 2) = packed;
}

// ---- MFMA MLP: P[n] = softmax(relu(h2[n]@dW + db)@oW + ob) ----
// 64 nodes/block; BTd[256][128] bf16; dense via MFMA, output layer fused in regs
__global__ __launch_bounds__(256) void k_mlp_mfma(const unsigned short* __restrict__ H2,
                                                  const unsigned short* __restrict__ BTd,
                                                  const float* __restrict__ db,
                                                  const float* __restrict__ oW,
                                                  const float* __restrict__ ob,
                                                  float* __restrict__ P) {
    __shared__ unsigned short As[64][136];
    __shared__ unsigned short Bs[128][136];
    int tid = threadIdx.x, lane = tid & 63, wave = tid >> 6;
    int quad = lane >> 4, l16 = lane & 15;
    int row0 = blockIdx.x * 64;
#pragma unroll
    for (int p = 0; p < 4; ++p) {
        int fid = tid + p * 256;
        int r = fid >> 4, c = fid & 15;
        int gr = row0 + r; if (gr > NN - 1) gr = NN - 1;
        *(uint4*)&As[r][c * 8] = *(const uint4*)(H2 + (size_t)gr * DD + c * 8);
    }
    short8 af[4];
    floatx4 acc[16];
#pragma unroll
    for (int i = 0; i < 16; ++i) acc[i] = (floatx4){0.f, 0.f, 0.f, 0.f};

    for (int ch = 0; ch < 2; ++ch) {
        __syncthreads();   // As ready (ch=0) / previous Bs readers done (ch=1)
#pragma unroll
        for (int p = 0; p < 8; ++p) {
            int fid = tid + p * 256;
            int r = fid >> 4, c = fid & 15;
            *(uint4*)&Bs[r][c * 8] = *(const uint4*)(BTd + (size_t)(ch * 128 + r) * DD + c * 8);
        }
        __syncthreads();
        if (ch == 0) {
#pragma unroll
            for (int ks = 0; ks < 4; ++ks)
                af[ks] = *(const short8*)&As[wave * 16 + l16][ks * 32 + quad * 8];
        }
#pragma unroll
        for (int ks = 0; ks < 4; ++ks) {
#pragma unroll
            for (int nt = 0; nt < 8; ++nt) {
                short8 bf = *(const short8*)&Bs[nt * 16 + l16][ks * 32 + quad * 8];
                acc[ch * 8 + nt] =
                    __builtin_amdgcn_mfma_f32_16x16x32_bf16(af[ks], bf, acc[ch * 8 + nt], 0, 0, 0);
            }
        }
    }
    // fused bias+relu+output-layer+softmax
    int rbase = row0 + wave * 16 + quad * 4;
#pragma unroll
    for (int r = 0; r < 4; ++r) {
        float p0 = 0.f, p1 = 0.f;
#pragma unroll
        for (int ch = 0; ch < 2; ++ch) {
#pragma unroll
            for (int nt = 0; nt < 8; ++nt) {
                int colc = ch * 128 + nt * 16 + l16;
                float h = acc[ch * 8 + nt][r] + db[colc];
                h = fmaxf(h, 0.f);
                p0 += h * oW[2 * colc];
                p1 += h * oW[2 * colc + 1];
            }
        }
#pragma unroll
        for (int m = 8; m >= 1; m >>= 1) {
            p0 += __shfl_xor(p0, m, 16);
            p1 += __shfl_xor(p1, m, 16);
        }
        if (l16 == 0) {
            int gr = rbase + r;
            if (gr < NN) {
                float l0 = p0 + ob[0], l1 = p1 + ob[1];
                float mx = fmaxf(l0, l1);
                float e0 = __expf(l0 - mx), e1 = __expf(l1 - mx);
                float inv = 1.f / (e0 + e1);
                float2 pr = {e0 * inv, e1 * inv};
                *(float2*)(P + 2 * gr) = pr;
            }
        }
    }
}

// ---- final gather: out[i] = P[oe_flat[set_idx[i]]] ----
__global__ void k_gather(const int* __restrict__ sidx, const int* __restrict__ oe,
                         const float* __restrict__ P, float* __restrict__ out) {
    int i = blockIdx.x * 256 + threadIdx.x;
    if (i >= NS) return;
    int node = oe[sidx[i]];
    float2 v = *(const float2*)(P + 2 * node);
    *(float2*)(out + 2 * i) = v;
}

extern "C" void kernel_launch(void* const* d_in, const int* in_sizes, int n_in,
                              void* d_out, int out_size, void* d_ws, size_t ws_size,
                              hipStream_t stream) {
    const float* node_state = (const float*)d_in[0];
    const int* ei   = (const int*)d_in[1];
    const int* oe   = (const int*)d_in[2];
    const int* sidx = (const int*)d_in[3];
    const float* W1 = (const float*)d_in[4];
    const float* b1 = (const float*)d_in[5];
    const float* W2 = (const float*)d_in[6];
    const float* b2 = (const float*)d_in[7];
    const float* dW = (const float*)d_in[8];
    const float* db = (const float*)d_in[9];
    const float* oW = (const float*)d_in[10];
    const float* ob = (const float*)d_in[11];
    float* out = (float*)d_out;

    char* ws = (char*)d_ws;
    size_t off = 0;
    auto carve = [&](size_t bytes) -> char* {
        char* p = ws + off;
        off = (off + bytes + 255) & ~(size_t)255;
        return p;
    };
    int*   deg     = (int*)carve((size_t)3 * NN * 4);   // deg_out | deg_in | cursor
    int*   cursor  = deg + 2 * NN;
    float* r       = (float*)carve((size_t)2 * NN * 4);
    int*   row_ptr = (int*)carve((size_t)(NN + 1) * 4);
    int*   col     = (int*)carve((size_t)NE * 4);
    unsigned short* t   = (unsigned short*)carve((size_t)NN * DD * 2);
    unsigned short* h   = (unsigned short*)carve((size_t)NN * DD * 2);
    unsigned short* BT1 = (unsigned short*)carve((size_t)DD * DD * 2);
    unsigned short* BT2 = (unsigned short*)carve((size_t)DD * DD * 2);
    unsigned short* BTd = (unsigned short*)carve((size_t)DD * NU * 2);
    float* P = (float*)t;   // alias: t dead after second aggregate

    float* r_out = r;
    float* r_in  = r + NN;
    int* deg_in  = deg + NN;

    // CSR build + weight prep
    hipMemsetAsync(deg, 0, (size_t)3 * NN * 4, stream);
    k_degree<<<(NE + 255) / 256, 256, 0, stream>>>(ei, deg);
    k_rsqrt<<<(2 * NN + 255) / 256, 256, 0, stream>>>(deg, r);
    k_scan<<<1, 1024, 0, stream>>>(deg_in, row_ptr);
    k_bucket<<<(NE + 255) / 256, 256, 0, stream>>>(ei, row_ptr, cursor, col);
    k_castT<<<(DD * DD + 255) / 256, 256, 0, stream>>>(W1, BT1, DD, DD);
    k_castT<<<(DD * DD + 255) / 256, 256, 0, stream>>>(W2, BT2, DD, DD);
    k_castT<<<(DD * NU + 255) / 256, 256, 0, stream>>>(dW, BTd, DD, NU);

    // layer 1
    k_gemm_bf<false><<<(NN + 63) / 64, 256, 0, stream>>>(node_state, r_out, BT1, t);
    k_aggregate<<<(NN + 3) / 4, 256, 0, stream>>>(t, row_ptr, col, r_in, b1, h);

    // layer 2
    k_gemm_bf<true><<<(NN + 63) / 64, 256, 0, stream>>>(h, r_out, BT2, t);
    k_aggregate<<<(NN + 3) / 4, 256, 0, stream>>>(t, row_ptr, col, r_in, b2, h);

    // per-node MLP + softmax, then gather
    k_mlp_mfma<<<(NN + 63) / 64, 256, 0, stream>>>(h, BTd, db, oW, ob, P);
    k_gather<<<(NS + 255) / 256, 256, 0, stream>>>(sidx, oe, P, out);
}

// Round 5
// 270.830 us; speedup vs baseline: 8.6062x; 1.2216x over previous
//
#include <hip/hip_runtime.h>

#define NN 50000
#define DD 128
#define NE 600000
#define NP 200000
#define NS 300000
#define NU 256
#define NBH 128
#define EPB 4688   // ceil(NE/NBH)
#define NW 12500   // NN/4 byte-packed words

typedef __attribute__((ext_vector_type(8))) short short8;
typedef __attribute__((ext_vector_type(4))) float floatx4;

__device__ inline float bf2f(unsigned int u16) {
    unsigned int x = u16 << 16;
    float f; __builtin_memcpy(&f, &x, 4); return f;
}
__device__ inline unsigned short f2bf(float f) {
    unsigned int x; __builtin_memcpy(&x, &f, 4);
    unsigned int lsb = (x >> 16) & 1u;
    x += 0x7fffu + lsb;
    return (unsigned short)(x >> 16);
}

// ---- per-block byte histograms: grid (NBH, 2); y=0 counts src, y=1 counts dst ----
__global__ __launch_bounds__(256) void k_hist(const int* __restrict__ ei,
                                              unsigned int* __restrict__ P) {
    __shared__ unsigned int hw[NW];
    int b = blockIdx.x, half = blockIdx.y, tid = threadIdx.x;
    for (int w = tid; w < NW; w += 256) hw[w] = 0;
    __syncthreads();
    const int* src = ei + (size_t)half * NE;
    int e0 = b * EPB, e1 = min(e0 + EPB, NE);
    for (int e = e0 + tid; e < e1; e += 256) {
        int s = src[e];
        atomicAdd(&hw[s >> 2], 1u << ((s & 3) * 8));
    }
    __syncthreads();
    unsigned int* Pb = P + ((size_t)half * NBH + b) * NW;
    for (int w = tid; w < NW; w += 256) Pb[w] = hw[w];
}

// ---- reduce partials -> deg_in ints + rsqrt for both halves ----
__global__ void k_reduce(const unsigned int* __restrict__ P, int* __restrict__ deg_in,
                         float* __restrict__ r) {
    int w = blockIdx.x * 256 + threadIdx.x;
    if (w >= 2 * NW) return;
    int half = (w >= NW);
    int wl = w - half * NW;
    const unsigned int* Ph = P + (size_t)half * NBH * NW + wl;
    int c0 = 0, c1 = 0, c2 = 0, c3 = 0;
    for (int b = 0; b < NBH; ++b) {
        unsigned int v = Ph[(size_t)b * NW];
        c0 += v & 0xff; c1 += (v >> 8) & 0xff; c2 += (v >> 16) & 0xff; c3 += v >> 24;
    }
    int nb = wl * 4;
    if (half) {
        int4 d = {c0, c1, c2, c3};
        *(int4*)(deg_in + nb) = d;
    }
    float4 rr = {rsqrtf((float)max(c0, 1)), rsqrtf((float)max(c1, 1)),
                 rsqrtf((float)max(c2, 1)), rsqrtf((float)max(c3, 1))};
    *(float4*)(r + (size_t)half * NN + nb) = rr;
}

// ---- single-block exclusive prefix sum (int4-wide) of deg_in -> row_ptr[NN+1] ----
__global__ __launch_bounds__(1024) void k_scan(const int* __restrict__ deg_in,
                                               int* __restrict__ row_ptr) {
    __shared__ int wsum[16];
    __shared__ int woff[16];
    __shared__ int carry_s;
    __shared__ int total_s;
    int tid = threadIdx.x, lane = tid & 63, w = tid >> 6;
    if (tid == 0) carry_s = 0;
    __syncthreads();
    for (int wb = 0; wb < NW; wb += 1024) {
        int i4 = wb + tid;
        int4 v = {0, 0, 0, 0};
        if (i4 < NW) v = *(const int4*)(deg_in + i4 * 4);
        int t0 = v.x, t1 = t0 + v.y, t2 = t1 + v.z, tot = t2 + v.w;
        int x = tot;
#pragma unroll
        for (int off = 1; off < 64; off <<= 1) {
            int y = __shfl_up(x, off);
            if (lane >= off) x += y;
        }
        if (lane == 63) wsum[w] = x;
        __syncthreads();
        if (w == 0 && lane < 16) {
            int s = wsum[lane];
            int xs = s;
#pragma unroll
            for (int off = 1; off < 16; off <<= 1) {
                int y = __shfl_up(xs, off);
                if (lane >= off) xs += y;
            }
            woff[lane] = xs - s;
            if (lane == 15) total_s = xs;
        }
        __syncthreads();
        if (i4 < NW) {
            int base = carry_s + woff[w] + x - tot;
            int4 o = {base, base + t0, base + t1, base + t2};
            *(int4*)(row_ptr + i4 * 4) = o;
        }
        __syncthreads();
        if (tid == 0) carry_s += total_s;
        __syncthreads();
    }
    if (tid == 0) row_ptr[NN] = carry_s;
}

// ---- per-(block,node) exclusive base offsets for counting-sort ----
__global__ void k_colscan(const unsigned int* __restrict__ Pin, const int* __restrict__ row_ptr,
                          int* __restrict__ basetab) {
    int n = blockIdx.x * 256 + threadIdx.x;
    if (n >= NN) return;
    int wl = n >> 2, sh = (n & 3) * 8;
    int run = row_ptr[n];
    for (int b = 0; b < NBH; ++b) {
        basetab[(size_t)b * NN + n] = run;
        run += (Pin[(size_t)b * NW + wl] >> sh) & 0xff;
    }
}

// ---- bucket edges, no global atomics: LDS byte cursor + per-block base ----
__global__ __launch_bounds__(256) void k_bucket2(const int* __restrict__ ei,
                                                 const int* __restrict__ basetab,
                                                 int* __restrict__ col) {
    __shared__ unsigned int cw[NW];
    int b = blockIdx.x, tid = threadIdx.x;
    for (int w = tid; w < NW; w += 256) cw[w] = 0;
    __syncthreads();
    const int* bt = basetab + (size_t)b * NN;
    int e0 = b * EPB, e1 = min(e0 + EPB, NE);
    for (int e = e0 + tid; e < e1; e += 256) {
        int s = ei[e], d = ei[NE + e];
        int sh = (d & 3) * 8;
        unsigned int old = atomicAdd(&cw[d >> 2], 1u << sh);
        int local = (old >> sh) & 0xff;
        col[bt[d] + local] = s;
    }
}

// ---- transpose + bf16-cast weights ----
__global__ void k_castT(const float* __restrict__ src, unsigned short* __restrict__ dst,
                        int R, int C) {
    int t = blockIdx.x * 256 + threadIdx.x;
    if (t < R * C) {
        int r = t / C, c = t - r * C;
        dst[c * R + r] = f2bf(src[t]);
    }
}

// ---- MFMA GEMM: Cm[64x128 bf16] = rowscale(A[64x128]) @ B, BT[128][128] bf16 ----
template <bool ABF>
__global__ __launch_bounds__(256) void k_gemm_bf(const void* __restrict__ Ap,
                                                 const float* __restrict__ rs,
                                                 const unsigned short* __restrict__ BT,
                                                 unsigned short* __restrict__ Cm) {
    __shared__ unsigned short As[64][136];
    __shared__ unsigned short Bs[128][136];
    int tid = threadIdx.x, lane = tid & 63, wave = tid >> 6;
    int quad = lane >> 4, l16 = lane & 15;
    int row0 = blockIdx.x * 64;

    if (ABF) {
        const unsigned short* A = (const unsigned short*)Ap;
#pragma unroll
        for (int p = 0; p < 4; ++p) {
            int fid = tid + p * 256;
            int r = fid >> 4, c = fid & 15;
            int gr = row0 + r; if (gr > NN - 1) gr = NN - 1;
            *(uint4*)&As[r][c * 8] = *(const uint4*)(A + (size_t)gr * DD + c * 8);
        }
    } else {
        const float* A = (const float*)Ap;
#pragma unroll
        for (int p = 0; p < 8; ++p) {
            int fid = tid + p * 256;
            int r = fid >> 5, c = fid & 31;
            int gr = row0 + r; if (gr > NN - 1) gr = NN - 1;
            float4 v = *(const float4*)(A + (size_t)gr * DD + c * 4);
            ushort4 u;
            u.x = f2bf(v.x); u.y = f2bf(v.y); u.z = f2bf(v.z); u.w = f2bf(v.w);
            *(ushort4*)&As[r][c * 4] = u;
        }
    }
#pragma unroll
    for (int p = 0; p < 8; ++p) {
        int fid = tid + p * 256;
        int r = fid >> 4, c = fid & 15;
        *(uint4*)&Bs[r][c * 8] = *(const uint4*)(BT + (size_t)r * DD + c * 8);
    }
    __syncthreads();

    short8 af[4];
#pragma unroll
    for (int ks = 0; ks < 4; ++ks)
        af[ks] = *(const short8*)&As[wave * 16 + l16][ks * 32 + quad * 8];
    floatx4 acc[8];
#pragma unroll
    for (int nt = 0; nt < 8; ++nt) acc[nt] = (floatx4){0.f, 0.f, 0.f, 0.f};
#pragma unroll
    for (int ks = 0; ks < 4; ++ks) {
#pragma unroll
        for (int nt = 0; nt < 8; ++nt) {
            short8 bf = *(const short8*)&Bs[nt * 16 + l16][ks * 32 + quad * 8];
            acc[nt] = __builtin_amdgcn_mfma_f32_16x16x32_bf16(af[ks], bf, acc[nt], 0, 0, 0);
        }
    }
    int rbase = row0 + wave * 16 + quad * 4;
#pragma unroll
    for (int r = 0; r < 4; ++r) {
        int gr = rbase + r;
        if (gr < NN) {
            float s = rs[gr];
#pragma unroll
            for (int nt = 0; nt < 8; ++nt)
                Cm[(size_t)gr * DD + nt * 16 + l16] = f2bf(acc[nt][r] * s);
        }
    }
}

// ---- CSR aggregate + fused finalize: H[n] = bf16((sum T[s]) * r_in[n] + b) ----
__global__ __launch_bounds__(256) void k_aggregate(const unsigned short* __restrict__ T,
                                                   const int* __restrict__ row_ptr,
                                                   const int* __restrict__ col,
                                                   const float* __restrict__ r_in,
                                                   const float* __restrict__ b,
                                                   unsigned short* __restrict__ H) {
    int node = blockIdx.x * 4 + (threadIdx.x >> 6);
    if (node >= NN) return;
    int lane = threadIdx.x & 63;
    int beg = row_ptr[node], end = row_ptr[node + 1];
    float a0 = 0.f, a1 = 0.f;
    for (int base = beg; base < end; base += 64) {
        int m = end - base; if (m > 64) m = 64;
        int myidx = (lane < m) ? col[base + lane] : 0;
        int j = 0;
        for (; j + 4 <= m; j += 4) {
            int s0 = __shfl(myidx, j), s1 = __shfl(myidx, j + 1);
            int s2 = __shfl(myidx, j + 2), s3 = __shfl(myidx, j + 3);
            unsigned int v0 = *(const unsigned int*)(T + (size_t)s0 * DD + lane * 2);
            unsigned int v1 = *(const unsigned int*)(T + (size_t)s1 * DD + lane * 2);
            unsigned int v2 = *(const unsigned int*)(T + (size_t)s2 * DD + lane * 2);
            unsigned int v3 = *(const unsigned int*)(T + (size_t)s3 * DD + lane * 2);
            a0 += bf2f(v0 & 0xffff) + bf2f(v1 & 0xffff) + bf2f(v2 & 0xffff) + bf2f(v3 & 0xffff);
            a1 += bf2f(v0 >> 16) + bf2f(v1 >> 16) + bf2f(v2 >> 16) + bf2f(v3 >> 16);
        }
        for (; j < m; ++j) {
            int s = __shfl(myidx, j);
            unsigned int v = *(const unsigned int*)(T + (size_t)s * DD + lane * 2);
            a0 += bf2f(v & 0xffff);
            a1 += bf2f(v >> 16);
        }
    }
    float rv = r_in[node];
    float o0 = a0 * rv + b[lane * 2];
    float o1 = a1 * rv + b[lane * 2 + 1];
    unsigned int packed = (unsigned int)f2bf(o0) | ((unsigned int)f2bf(o1) << 16);
    *(unsigned int*)(H + (size_t)node * DD + lane * 2) = packed;
}

// ---- MFMA MLP: P[n] = softmax(relu(h2[n]@dW + db)@oW + ob) ----
__global__ __launch_bounds__(256) void k_mlp_mfma(const unsigned short* __restrict__ H2,
                                                  const unsigned short* __restrict__ BTd,
                                                  const float* __restrict__ db,
                                                  const float* __restrict__ oW,
                                                  const float* __restrict__ ob,
                                                  float* __restrict__ P) {
    __shared__ unsigned short As[64][136];
    __shared__ unsigned short Bs[128][136];
    int tid = threadIdx.x, lane = tid & 63, wave = tid >> 6;
    int quad = lane >> 4, l16 = lane & 15;
    int row0 = blockIdx.x * 64;
#pragma unroll
    for (int p = 0; p < 4; ++p) {
        int fid = tid + p * 256;
        int r = fid >> 4, c = fid & 15;
        int gr = row0 + r; if (gr > NN - 1) gr = NN - 1;
        *(uint4*)&As[r][c * 8] = *(const uint4*)(H2 + (size_t)gr * DD + c * 8);
    }
    short8 af[4];
    floatx4 acc[16];
#pragma unroll
    for (int i = 0; i < 16; ++i) acc[i] = (floatx4){0.f, 0.f, 0.f, 0.f};

    for (int ch = 0; ch < 2; ++ch) {
        __syncthreads();
#pragma unroll
        for (int p = 0; p < 8; ++p) {
            int fid = tid + p * 256;
            int r = fid >> 4, c = fid & 15;
            *(uint4*)&Bs[r][c * 8] = *(const uint4*)(BTd + (size_t)(ch * 128 + r) * DD + c * 8);
        }
        __syncthreads();
        if (ch == 0) {
#pragma unroll
            for (int ks = 0; ks < 4; ++ks)
                af[ks] = *(const short8*)&As[wave * 16 + l16][ks * 32 + quad * 8];
        }
#pragma unroll
        for (int ks = 0; ks < 4; ++ks) {
#pragma unroll
            for (int nt = 0; nt < 8; ++nt) {
                short8 bf = *(const short8*)&Bs[nt * 16 + l16][ks * 32 + quad * 8];
                acc[ch * 8 + nt] =
                    __builtin_amdgcn_mfma_f32_16x16x32_bf16(af[ks], bf, acc[ch * 8 + nt], 0, 0, 0);
            }
        }
    }
    int rbase = row0 + wave * 16 + quad * 4;
#pragma unroll
    for (int r = 0; r < 4; ++r) {
        float p0 = 0.f, p1 = 0.f;
#pragma unroll
        for (int ch = 0; ch < 2; ++ch) {
#pragma unroll
            for (int nt = 0; nt < 8; ++nt) {
                int colc = ch * 128 + nt * 16 + l16;
                float h = acc[ch * 8 + nt][r] + db[colc];
                h = fmaxf(h, 0.f);
                p0 += h * oW[2 * colc];
                p1 += h * oW[2 * colc + 1];
            }
        }
#pragma unroll
        for (int m = 8; m >= 1; m >>= 1) {
            p0 += __shfl_xor(p0, m, 16);
            p1 += __shfl_xor(p1, m, 16);
        }
        if (l16 == 0) {
            int gr = rbase + r;
            if (gr < NN) {
                float l0 = p0 + ob[0], l1 = p1 + ob[1];
                float mx = fmaxf(l0, l1);
                float e0 = __expf(l0 - mx), e1 = __expf(l1 - mx);
                float inv = 1.f / (e0 + e1);
                float2 pr = {e0 * inv, e1 * inv};
                *(float2*)(P + 2 * gr) = pr;
            }
        }
    }
}

// ---- final gather ----
__global__ void k_gather(const int* __restrict__ sidx, const int* __restrict__ oe,
                         const float* __restrict__ P, float* __restrict__ out) {
    int i = blockIdx.x * 256 + threadIdx.x;
    if (i >= NS) return;
    int node = oe[sidx[i]];
    float2 v = *(const float2*)(P + 2 * node);
    *(float2*)(out + 2 * i) = v;
}

extern "C" void kernel_launch(void* const* d_in, const int* in_sizes, int n_in,
                              void* d_out, int out_size, void* d_ws, size_t ws_size,
                              hipStream_t stream) {
    const float* node_state = (const float*)d_in[0];
    const int* ei   = (const int*)d_in[1];
    const int* oe   = (const int*)d_in[2];
    const int* sidx = (const int*)d_in[3];
    const float* W1 = (const float*)d_in[4];
    const float* b1 = (const float*)d_in[5];
    const float* W2 = (const float*)d_in[6];
    const float* b2 = (const float*)d_in[7];
    const float* dW = (const float*)d_in[8];
    const float* db = (const float*)d_in[9];
    const float* oW = (const float*)d_in[10];
    const float* ob = (const float*)d_in[11];
    float* out = (float*)d_out;

    char* ws = (char*)d_ws;
    size_t off = 0;
    auto carve = [&](size_t bytes) -> char* {
        char* p = ws + off;
        off = (off + bytes + 255) & ~(size_t)255;
        return p;
    };
    int*   deg_in  = (int*)carve((size_t)NN * 4);
    float* r       = (float*)carve((size_t)2 * NN * 4);
    int*   row_ptr = (int*)carve((size_t)(NN + 1) * 4);
    int*   col     = (int*)carve((size_t)NE * 4);
    unsigned int* P_hist = (unsigned int*)carve((size_t)2 * NBH * NW * 4);
    int*   basetab = (int*)carve((size_t)NBH * NN * 4);
    unsigned short* t   = (unsigned short*)carve((size_t)NN * DD * 2);
    unsigned short* h   = (unsigned short*)carve((size_t)NN * DD * 2);
    unsigned short* BT1 = (unsigned short*)carve((size_t)DD * DD * 2);
    unsigned short* BT2 = (unsigned short*)carve((size_t)DD * DD * 2);
    unsigned short* BTd = (unsigned short*)carve((size_t)DD * NU * 2);
    float* P = (float*)t;   // alias: t dead after second aggregate

    float* r_out = r;
    float* r_in  = r + NN;

    // CSR build — no global atomics
    k_hist<<<dim3(NBH, 2), 256, 0, stream>>>(ei, P_hist);
    k_reduce<<<(2 * NW + 255) / 256, 256, 0, stream>>>(P_hist, deg_in, r);
    k_scan<<<1, 1024, 0, stream>>>(deg_in, row_ptr);
    k_colscan<<<(NN + 255) / 256, 256, 0, stream>>>(P_hist + (size_t)NBH * NW, row_ptr, basetab);
    k_bucket2<<<NBH, 256, 0, stream>>>(ei, basetab, col);

    // weight prep
    k_castT<<<(DD * DD + 255) / 256, 256, 0, stream>>>(W1, BT1, DD, DD);
    k_castT<<<(DD * DD + 255) / 256, 256, 0, stream>>>(W2, BT2, DD, DD);
    k_castT<<<(DD * NU + 255) / 256, 256, 0, stream>>>(dW, BTd, DD, NU);

    // layer 1
    k_gemm_bf<false><<<(NN + 63) / 64, 256, 0, stream>>>(node_state, r_out, BT1, t);
    k_aggregate<<<(NN + 3) / 4, 256, 0, stream>>>(t, row_ptr, col, r_in, b1, h);

    // layer 2
    k_gemm_bf<true><<<(NN + 63) / 64, 256, 0, stream>>>(h, r_out, BT2, t);
    k_aggregate<<<(NN + 3) / 4, 256, 0, stream>>>(t, row_ptr, col, r_in, b2, h);

    // per-node MLP + softmax, then gather
    k_mlp_mfma<<<(NN + 63) / 64, 256, 0, stream>>>(h, BTd, db, oW, ob, P);
    k_gather<<<(NS + 255) / 256, 256, 0, stream>>>(sidx, oe, P, out);
}